// Round 1
// baseline (228.357 us; speedup 1.0000x reference)
//
#include <hip/hip_runtime.h>
#include <math.h>

#define DIM 512
#define D4  128      // DIM/4
#define CBS 256
#define NCB 8
#define BT  8        // batch tile for GEMM-shaped kernels

// ---------------------------------------------------------------------------
// K0: logits = (x @ w^T + b) * 4 ; argmax over each codebook's 256 entries.
// grid = (B/BT, NCB), block = 256 (one thread per codebook entry k).
// ---------------------------------------------------------------------------
__global__ __launch_bounds__(256) void k_logits_argmax(
    const float* __restrict__ x, const float* __restrict__ w,
    const float* __restrict__ bias, int* __restrict__ idx_out)
{
    __shared__ float xs[BT][DIM];
    __shared__ float rv[256];
    __shared__ int   ri[256];
    const int tid = threadIdx.x;
    const int b0  = blockIdx.x * BT;
    const int c   = blockIdx.y;

    for (int lin = tid; lin < BT * D4; lin += 256) {
        int bi = lin >> 7, t = lin & 127;
        ((float4*)xs[bi])[t] =
            ((const float4*)(x + (size_t)(b0 + bi) * DIM))[t];
    }
    __syncthreads();

    const int j = c * CBS + tid;
    const float4* wr = (const float4*)(w + (size_t)j * DIM);
    float acc[BT];
#pragma unroll
    for (int bi = 0; bi < BT; ++bi) acc[bi] = 0.f;
    for (int t = 0; t < D4; ++t) {
        float4 wv = wr[t];
#pragma unroll
        for (int bi = 0; bi < BT; ++bi) {
            float4 xv = ((const float4*)xs[bi])[t];
            acc[bi] = fmaf(wv.x, xv.x, acc[bi]);
            acc[bi] = fmaf(wv.y, xv.y, acc[bi]);
            acc[bi] = fmaf(wv.z, xv.z, acc[bi]);
            acc[bi] = fmaf(wv.w, xv.w, acc[bi]);
        }
    }
    float bj = bias[j];
#pragma unroll
    for (int bi = 0; bi < BT; ++bi) acc[bi] = (acc[bi] + bj) * 4.0f;

    for (int bi = 0; bi < BT; ++bi) {
        rv[tid] = acc[bi]; ri[tid] = tid;
        __syncthreads();
        for (int s = 128; s > 0; s >>= 1) {
            if (tid < s) {
                float v2 = rv[tid + s]; int i2 = ri[tid + s];
                if (v2 > rv[tid] || (v2 == rv[tid] && i2 < ri[tid])) {
                    rv[tid] = v2; ri[tid] = i2;
                }
            }
            __syncthreads();
        }
        if (tid == 0) idx_out[(b0 + bi) * NCB + c] = ri[0];
        __syncthreads();
    }
}

// ---------------------------------------------------------------------------
// C2: c2[j] = ||centers_row_j||^2 for j in [0, NCB*CBS). grid=8, block=256.
// ---------------------------------------------------------------------------
__global__ __launch_bounds__(256) void k_c2(
    const float* __restrict__ centers, float* __restrict__ c2)
{
    int j = blockIdx.x * 256 + threadIdx.x;
    const float4* r = (const float4*)(centers + (size_t)j * DIM);
    float s = 0.f;
    for (int t = 0; t < D4; ++t) {
        float4 v = r[t];
        s = fmaf(v.x, v.x, s); s = fmaf(v.y, v.y, s);
        s = fmaf(v.z, v.z, s); s = fmaf(v.w, v.w, s);
    }
    c2[j] = s;
}

// ---------------------------------------------------------------------------
// R1: x_err[b] = sum_c centers[c, idx[b,c]] - x[b].  grid=B, block=128.
// ---------------------------------------------------------------------------
__global__ __launch_bounds__(128) void k_xerr(
    const float* __restrict__ x, const float* __restrict__ centers,
    const int* __restrict__ idx, float* __restrict__ xerr)
{
    int b = blockIdx.x, t = threadIdx.x;
    float4 a = ((const float4*)(x + (size_t)b * DIM))[t];
    float4 s = { -a.x, -a.y, -a.z, -a.w };
#pragma unroll
    for (int c = 0; c < NCB; ++c) {
        int j = c * CBS + idx[b * NCB + c];
        float4 v = ((const float4*)(centers + (size_t)j * DIM))[t];
        s.x += v.x; s.y += v.y; s.z += v.z; s.w += v.w;
    }
    ((float4*)(xerr + (size_t)b * DIM))[t] = s;
}

// ---------------------------------------------------------------------------
// R2: per (b,c): base = x_err[b] - centers[c, idx[b,c]];
//     score[k] = -((||base||^2 + c2[c,k]) + 2*dot(base, centers[c,k]));
//     mask k==idx; proposed[b,c] = argmax_k.  grid=(B/BT, NCB), block=256.
// ---------------------------------------------------------------------------
__global__ __launch_bounds__(256) void k_propose(
    const float* __restrict__ xerr, const float* __restrict__ centers,
    const float* __restrict__ c2, const int* __restrict__ idx,
    int* __restrict__ proposed)
{
    __shared__ float bs[BT][DIM];
    __shared__ float base2[BT];
    __shared__ int   idxs[BT];
    __shared__ float rv[256];
    __shared__ int   ri[256];
    const int tid = threadIdx.x;
    const int b0  = blockIdx.x * BT;
    const int c   = blockIdx.y;

    if (tid < BT) idxs[tid] = idx[(b0 + tid) * NCB + c];
    __syncthreads();

    for (int lin = tid; lin < BT * D4; lin += 256) {
        int bi = lin >> 7, t = lin & 127;
        float4 e = ((const float4*)(xerr + (size_t)(b0 + bi) * DIM))[t];
        float4 v = ((const float4*)(centers +
                    (size_t)(c * CBS + idxs[bi]) * DIM))[t];
        float4 r = { e.x - v.x, e.y - v.y, e.z - v.z, e.w - v.w };
        ((float4*)bs[bi])[t] = r;
    }
    __syncthreads();

    for (int bi = 0; bi < BT; ++bi) {
        float a0 = bs[bi][tid], a1 = bs[bi][tid + 256];
        rv[tid] = a0 * a0 + a1 * a1;
        __syncthreads();
        for (int s = 128; s > 0; s >>= 1) {
            if (tid < s) rv[tid] += rv[tid + s];
            __syncthreads();
        }
        if (tid == 0) base2[bi] = rv[0];
        __syncthreads();
    }

    const int j = c * CBS + tid;
    const float4* wr = (const float4*)(centers + (size_t)j * DIM);
    float acc[BT];
#pragma unroll
    for (int bi = 0; bi < BT; ++bi) acc[bi] = 0.f;
    for (int t = 0; t < D4; ++t) {
        float4 wv = wr[t];
#pragma unroll
        for (int bi = 0; bi < BT; ++bi) {
            float4 xv = ((const float4*)bs[bi])[t];
            acc[bi] = fmaf(wv.x, xv.x, acc[bi]);
            acc[bi] = fmaf(wv.y, xv.y, acc[bi]);
            acc[bi] = fmaf(wv.z, xv.z, acc[bi]);
            acc[bi] = fmaf(wv.w, xv.w, acc[bi]);
        }
    }
    float c2j = c2[j];
    for (int bi = 0; bi < BT; ++bi) {
        float score = -((base2[bi] + c2j) + 2.0f * acc[bi]);
        if (tid == idxs[bi]) score = -INFINITY;
        rv[tid] = score; ri[tid] = tid;
        __syncthreads();
        for (int s = 128; s > 0; s >>= 1) {
            if (tid < s) {
                float v2 = rv[tid + s]; int i2 = ri[tid + s];
                if (v2 > rv[tid] || (v2 == rv[tid] && i2 < ri[tid])) {
                    rv[tid] = v2; ri[tid] = i2;
                }
            }
            __syncthreads();
        }
        if (tid == 0) proposed[(b0 + bi) * NCB + c] = ri[0];
        __syncthreads();
    }
}

// ---------------------------------------------------------------------------
// R3: per b: deltas[c] = centers[c,prop]-centers[c,idx];
//     err[p] = ||x_err + sum_{c: bit c of p == 0} deltas[c]||^2;
//     p* = argmin; for c with bit c of p* == 0: idx[b,c] = prop[b,c].
//     grid=B, block=256 (one thread per subset p).
// ---------------------------------------------------------------------------
__global__ __launch_bounds__(256) void k_subset(
    const float* __restrict__ xerr, const float* __restrict__ centers,
    const int* __restrict__ proposed, int* __restrict__ idx)
{
    __shared__ float dl[NCB][DIM];
    __shared__ float xe[DIM];
    __shared__ int   cidx[NCB], cprop[NCB];
    __shared__ float rv[256];
    __shared__ int   ri[256];
    const int tid = threadIdx.x;
    const int b   = blockIdx.x;

    if (tid < NCB) {
        cidx[tid]  = idx[b * NCB + tid];
        cprop[tid] = proposed[b * NCB + tid];
    }
    __syncthreads();

    for (int lin = tid; lin < NCB * D4; lin += 256) {
        int cc = lin >> 7, t = lin & 127;
        float4 a = ((const float4*)(centers +
                    (size_t)(cc * CBS + cprop[cc]) * DIM))[t];
        float4 o = ((const float4*)(centers +
                    (size_t)(cc * CBS + cidx[cc]) * DIM))[t];
        float4 r = { a.x - o.x, a.y - o.y, a.z - o.z, a.w - o.w };
        ((float4*)dl[cc])[t] = r;
    }
    if (tid < D4)
        ((float4*)xe)[tid] = ((const float4*)(xerr + (size_t)b * DIM))[tid];
    __syncthreads();

    float sel[NCB];
#pragma unroll
    for (int c = 0; c < NCB; ++c)
        sel[c] = ((tid >> c) & 1) ? 0.f : 1.f;

    float err = 0.f;
    for (int t = 0; t < D4; ++t) {
        float4 e = ((const float4*)xe)[t];
        float ad0 = e.x, ad1 = e.y, ad2 = e.z, ad3 = e.w;
#pragma unroll
        for (int c = 0; c < NCB; ++c) {
            float4 dv = ((const float4*)dl[c])[t];
            ad0 = fmaf(sel[c], dv.x, ad0);
            ad1 = fmaf(sel[c], dv.y, ad1);
            ad2 = fmaf(sel[c], dv.z, ad2);
            ad3 = fmaf(sel[c], dv.w, ad3);
        }
        err = fmaf(ad0, ad0, err);
        err = fmaf(ad1, ad1, err);
        err = fmaf(ad2, ad2, err);
        err = fmaf(ad3, ad3, err);
    }

    rv[tid] = err; ri[tid] = tid;
    __syncthreads();
    for (int s = 128; s > 0; s >>= 1) {
        if (tid < s) {
            float v2 = rv[tid + s]; int i2 = ri[tid + s];
            if (v2 < rv[tid] || (v2 == rv[tid] && i2 < ri[tid])) {
                rv[tid] = v2; ri[tid] = i2;
            }
        }
        __syncthreads();
    }
    int bp = ri[0];
    if (tid < NCB) {
        if (((bp >> tid) & 1) == 0)
            idx[b * NCB + tid] = cprop[tid];
    }
}

// ---------------------------------------------------------------------------
extern "C" void kernel_launch(void* const* d_in, const int* in_sizes, int n_in,
                              void* d_out, int out_size, void* d_ws, size_t ws_size,
                              hipStream_t stream)
{
    const float* x    = (const float*)d_in[0];
    const float* w    = (const float*)d_in[1];
    const float* bl   = (const float*)d_in[2];
    const float* cent = (const float*)d_in[3];
    int* idx = (int*)d_out;

    const int B = in_sizes[0] / DIM;   // 512

    char* ws = (char*)d_ws;
    float* c2   = (float*)ws;                          // NCB*CBS floats (8 KB)
    float* xerr = (float*)(ws + 8192);                 // B*DIM floats (1 MB)
    int*   prop = (int*)(ws + 8192 + (size_t)B * DIM * 4); // B*NCB ints (16 KB)

    dim3 gg(B / BT, NCB);
    k_logits_argmax<<<gg, 256, 0, stream>>>(x, w, bl, idx);
    k_c2<<<NCB * CBS / 256, 256, 0, stream>>>(cent, c2);
    for (int it = 0; it < 2; ++it) {
        k_xerr<<<B, 128, 0, stream>>>(x, cent, idx, xerr);
        k_propose<<<gg, 256, 0, stream>>>(xerr, cent, c2, idx, prop);
        k_subset<<<B, 256, 0, stream>>>(xerr, cent, prop, idx);
    }
}